// Round 2
// baseline (35255.804 us; speedup 1.0000x reference)
//
#include <hip/hip_runtime.h>
#include <stdint.h>

#define T_ 512
#define B_ 64
#define V_ 256
#define H_ 1024

typedef short short8 __attribute__((ext_vector_type(8)));
typedef float float4_ __attribute__((ext_vector_type(4)));
typedef unsigned short ushort_t;
typedef unsigned long long ull;

__device__ __forceinline__ float sigf(float x){ return 1.0f/(1.0f + __expf(-x)); }
__device__ __forceinline__ float tanhfast(float x){ return 1.0f - 2.0f/(__expf(2.0f*x) + 1.0f); }
// RNE float->bf16 (finite values only; no NaN in this problem)
__device__ __forceinline__ ushort_t f2bf(float x){
  uint32_t u = __float_as_uint(x);
  uint32_t r = (u + 0x7FFFu + ((u >> 16) & 1u)) >> 16;
  return (ushort_t)r;
}

// ---------------- prep kernels ----------------
__global__ void k_cvt(const float* __restrict__ in, ushort_t* __restrict__ out, int n){
  int i = blockIdx.x*256 + threadIdx.x;
  if (i < n) out[i] = f2bf(in[i]);
}

// layer0 packed weights: Wpk0[p][k], K=1280. p=4*j+gate, col=gate*1024+j.
// k<256 -> Wih0[col][k]; else Whh0[col][k-256]
__global__ void k_pack0(const float* __restrict__ Wih0, const float* __restrict__ Whh0,
                        ushort_t* __restrict__ Wpk){
  int i = blockIdx.x*256 + threadIdx.x;
  if (i >= 4096*1280) return;
  int p = i / 1280, k = i - p*1280;
  int col = (p & 3)*1024 + (p >> 2);
  float v = (k < 256) ? Wih0[col*256 + k] : Whh0[col*1024 + (k - 256)];
  Wpk[i] = f2bf(v);
}

// layers 1/2: Wpk[p][k], K=2048. k<1024 -> Wih[col][k]; else Whh[col][k-1024]
__global__ void k_pack12(const float* __restrict__ Wih, const float* __restrict__ Whh,
                         ushort_t* __restrict__ Wpk){
  int i = blockIdx.x*256 + threadIdx.x;
  if (i >= 4096*2048) return;
  int p = i >> 11, k = i & 2047;
  int col = (p & 3)*1024 + (p >> 2);
  float v = (k < 1024) ? Wih[col*1024 + k] : Whh[col*1024 + (k - 1024)];
  Wpk[i] = f2bf(v);
}

__global__ void k_bias(const float* __restrict__ bih0, const float* __restrict__ bhh0,
                       const float* __restrict__ bihR, const float* __restrict__ bhhR,
                       float* __restrict__ biaspk){
  int i = blockIdx.x*256 + threadIdx.x;
  if (i >= 3*4096) return;
  int l = i >> 12, p = i & 4095;
  int col = (p & 3)*1024 + (p >> 2);
  float v = (l == 0) ? (bih0[col] + bhh0[col])
                     : (bihR[(l-1)*4096 + col] + bhhR[(l-1)*4096 + col]);
  biaspk[i] = v;
}

__global__ void k_zero(ull* __restrict__ h, int n_ull, int* __restrict__ syncp){
  int i = blockIdx.x*256 + threadIdx.x;
  if (i < n_ull) h[i] = 0ull;
  if (i == 0){ syncp[0] = 0; syncp[1] = 0; }
}

// ---------------- persistent pipelined LSTM ----------------
// 192 blocks: group g = bid>>6 (layer), cb = bid&63 -> owns gate-cols p in [64*cb, 64*cb+64)
// i.e. hidden j in [16*cb, 16*cb+16). 4 waves split K. h ping-pong in global bf16.
__global__ __launch_bounds__(256, 1) void k_lstm(
    const ushort_t* __restrict__ xin,   // [T][B][256] bf16 one-hot
    const ushort_t* __restrict__ Wpk0,
    const ushort_t* __restrict__ Wpk1,
    const ushort_t* __restrict__ Wpk2,
    const float*  __restrict__ biaspk,  // [3][4096]
    ushort_t* y0, ushort_t* y1, ushort_t* y2,  // [T][B][H] bf16 (no restrict: aliased roles)
    ull* hbuf,                          // [3][2][B*H/4]
    int* syncp)
{
  const int tid  = threadIdx.x;
  const int lane = tid & 63;
  const int wv   = tid >> 6;
  const int g    = blockIdx.x >> 6;
  const int cb   = blockIdx.x & 63;
  const int p0   = cb * 64;
  const int j0   = cb * 16;

  const int Kx = (g == 0) ? 256 : 1024;
  const int K  = Kx + 1024;
  const ushort_t* xsrc = (g == 0) ? xin : (g == 1 ? y0 : y1);
  ushort_t* yout       = (g == 0) ? y0  : (g == 1 ? y1 : y2);
  const ushort_t* Wpk  = (g == 0) ? Wpk0 : (g == 1 ? Wpk1 : Wpk2);
  const float* bias = biaspk + g*4096;
  ull* hb0 = hbuf + (size_t)g * 2 * (B_*H_/4);

  const int Ks = K >> 2;          // per-wave K slice (320 or 512), multiple of 64
  const int ks = wv * Ks, ke = ks + Ks;

  __shared__ float red[2][64][68];   // 34.8 KB partial-sum buffer (padded)

  const int eb = tid >> 2;   // elementwise: batch
  const int jq = tid & 3;    // j quad -> j_local = jq*4 + r
  float c_reg[4] = {0.f, 0.f, 0.f, 0.f};

  int* cnt = syncp; int* gen = syncp + 1;

  for (int s = 0; s < T_ + 2; ++s){
    int t = s - g;
    if (t >= 0 && t < T_){
      const ushort_t* xt = xsrc + (size_t)t * B_ * Kx;
      ull* hcur = hb0 + (size_t)(t & 1) * (B_*H_/4);
      ull* hnxt = hb0 + (size_t)((t + 1) & 1) * (B_*H_/4);

      float4_ acc[4][4];
      #pragma unroll
      for (int a = 0; a < 4; ++a)
        #pragma unroll
        for (int b = 0; b < 4; ++b){ float4_ z = {0.f,0.f,0.f,0.f}; acc[a][b] = z; }

      // K loop in chunks of 64 (2 MFMA k-steps); chunks never straddle x/h boundary
      for (int k0 = ks; k0 < ke; k0 += 64){
        short8 av[4][2];
        if (k0 < Kx){
          #pragma unroll
          for (int bt = 0; bt < 4; ++bt){
            int m = bt*16 + (lane & 15);
            const ushort_t* pa = xt + (size_t)m * Kx + k0 + ((lane >> 4) << 3);
            av[bt][0] = *(const short8*)pa;
            av[bt][1] = *(const short8*)(pa + 32);
          }
        } else {
          #pragma unroll
          for (int bt = 0; bt < 4; ++bt){
            int m = bt*16 + (lane & 15);
            size_t eo = (size_t)m * 1024 + (k0 - Kx) + ((lane >> 4) << 3);
            ull* ph = hcur + (eo >> 2);
            ull t0a = __hip_atomic_load(ph,     __ATOMIC_RELAXED, __HIP_MEMORY_SCOPE_AGENT);
            ull t1a = __hip_atomic_load(ph + 1, __ATOMIC_RELAXED, __HIP_MEMORY_SCOPE_AGENT);
            ull t2a = __hip_atomic_load(ph + 8, __ATOMIC_RELAXED, __HIP_MEMORY_SCOPE_AGENT);
            ull t3a = __hip_atomic_load(ph + 9, __ATOMIC_RELAXED, __HIP_MEMORY_SCOPE_AGENT);
            ull tmp[2];
            tmp[0] = t0a; tmp[1] = t1a; __builtin_memcpy(&av[bt][0], tmp, 16);
            tmp[0] = t2a; tmp[1] = t3a; __builtin_memcpy(&av[bt][1], tmp, 16);
          }
        }
        #pragma unroll
        for (int ct = 0; ct < 4; ++ct){
          int pcol = p0 + ct*16 + (lane & 15);
          const ushort_t* pb = Wpk + (size_t)pcol * K + k0 + ((lane >> 4) << 3);
          short8 bv0 = *(const short8*)pb;
          short8 bv1 = *(const short8*)(pb + 32);
          #pragma unroll
          for (int bt = 0; bt < 4; ++bt){
            acc[bt][ct] = __builtin_amdgcn_mfma_f32_16x16x32_bf16(av[bt][0], bv0, acc[bt][ct], 0, 0, 0);
            acc[bt][ct] = __builtin_amdgcn_mfma_f32_16x16x32_bf16(av[bt][1], bv1, acc[bt][ct], 0, 0, 0);
          }
        }
      }

      // cross-wave reduction via LDS (2-stage to stay under 64 KB static LDS)
      if (wv < 2){
        #pragma unroll
        for (int bt = 0; bt < 4; ++bt){
          int row = bt*16 + ((lane >> 4) << 2);
          #pragma unroll
          for (int ct = 0; ct < 4; ++ct){
            int colb = ct*16 + (lane & 15);
            #pragma unroll
            for (int r = 0; r < 4; ++r) red[wv][row + r][colb] = acc[bt][ct][r];
          }
        }
      }
      __syncthreads();
      if (wv >= 2){
        #pragma unroll
        for (int bt = 0; bt < 4; ++bt){
          int row = bt*16 + ((lane >> 4) << 2);
          #pragma unroll
          for (int ct = 0; ct < 4; ++ct){
            int colb = ct*16 + (lane & 15);
            #pragma unroll
            for (int r = 0; r < 4; ++r) red[wv - 2][row + r][colb] += acc[bt][ct][r];
          }
        }
      }
      __syncthreads();

      // elementwise LSTM cell for (eb, j_local = jq*4 + r)
      ull hpack = 0ull;
      #pragma unroll
      for (int r = 0; r < 4; ++r){
        int jl = jq*4 + r;
        float4_ a0 = *(float4_*)&red[0][eb][jl*4];
        float4_ a1 = *(float4_*)&red[1][eb][jl*4];
        float4_ bsv = *(const float4_*)(bias + p0 + jl*4);
        float4_ gsv = a0 + a1 + bsv;
        float iv = sigf(gsv.x);
        float fv = sigf(gsv.y);
        float gv = tanhfast(gsv.z);
        float ov = sigf(gsv.w);
        float cv = fv * c_reg[r] + iv * gv;
        c_reg[r] = cv;
        float hv = ov * tanhfast(cv);
        hpack |= ((ull)f2bf(hv)) << (16 * r);
      }
      size_t eo = (size_t)eb * 1024 + j0 + jq*4;
      __hip_atomic_store(hnxt + (eo >> 2), hpack, __ATOMIC_RELAXED, __HIP_MEMORY_SCOPE_AGENT);
      *(ull*)(yout + (size_t)t * B_ * H_ + eo) = hpack;
    }

    // grid barrier (192 blocks, co-resident by construction)
    // release: make this thread's h/y stores visible at agent scope before arrival
    __builtin_amdgcn_fence(__ATOMIC_RELEASE, "agent");
    __syncthreads();
    if (tid == 0){
      int gv = __hip_atomic_load(gen, __ATOMIC_RELAXED, __HIP_MEMORY_SCOPE_AGENT);
      int a = __hip_atomic_fetch_add(cnt, 1, __ATOMIC_ACQ_REL, __HIP_MEMORY_SCOPE_AGENT);
      if (a == 191){
        __hip_atomic_store(cnt, 0, __ATOMIC_RELAXED, __HIP_MEMORY_SCOPE_AGENT);
        __hip_atomic_store(gen, gv + 1, __ATOMIC_RELEASE, __HIP_MEMORY_SCOPE_AGENT);
      } else {
        while (__hip_atomic_load(gen, __ATOMIC_ACQUIRE, __HIP_MEMORY_SCOPE_AGENT) == gv){
          __builtin_amdgcn_s_sleep(4);
        }
      }
    }
    __syncthreads();
    // acquire: make other blocks' stores visible to this thread's subsequent loads
    __builtin_amdgcn_fence(__ATOMIC_ACQUIRE, "agent");
  }
}

// ---------------- output projection ----------------
// out[b][v][t] = (t < len[b]) ? y2[t,b,:]·Wout[v,:] + bout[v] : bout[v]
__global__ __launch_bounds__(256, 1) void k_out(
    const ushort_t* __restrict__ y2, const ushort_t* __restrict__ Woutb,
    const float* __restrict__ bout, const int* __restrict__ lengths,
    float* __restrict__ dout)
{
  int tid = threadIdx.x, lane = tid & 63, wv = tid >> 6;
  int bid = blockIdx.x;
  int b = bid >> 5;
  int rem = bid & 31;
  int vv = rem >> 3, tt = rem & 7;
  int t0 = tt*64 + wv*16;
  float4_ acc[4];
  #pragma unroll
  for (int i = 0; i < 4; ++i){ float4_ z = {0.f,0.f,0.f,0.f}; acc[i] = z; }
  int m = lane & 15, kq = lane >> 4;
  const ushort_t* ya = y2 + ((size_t)(t0 + m) * B_ + b) * H_ + (kq << 3);
  for (int k0 = 0; k0 < 1024; k0 += 32){
    short8 af = *(const short8*)(ya + k0);
    #pragma unroll
    for (int ct = 0; ct < 4; ++ct){
      int v = vv*64 + ct*16 + m;
      short8 bf = *(const short8*)(Woutb + (size_t)v * H_ + k0 + (kq << 3));
      acc[ct] = __builtin_amdgcn_mfma_f32_16x16x32_bf16(af, bf, acc[ct], 0, 0, 0);
    }
  }
  int len = lengths[b];
  int tb = t0 + (kq << 2);
  #pragma unroll
  for (int ct = 0; ct < 4; ++ct){
    int v = vv*64 + ct*16 + m;
    float bo = bout[v];
    float4_ res;
    #pragma unroll
    for (int r = 0; r < 4; ++r){
      int tcur = tb + r;
      res[r] = (tcur < len) ? (acc[ct][r] + bo) : bo;
    }
    *(float4_*)(dout + ((size_t)b * V_ + v) * T_ + tb) = res;
  }
}

extern "C" void kernel_launch(void* const* d_in, const int* in_sizes, int n_in,
                              void* d_out, int out_size, void* d_ws, size_t ws_size,
                              hipStream_t stream){
  const float* inputs = (const float*)d_in[0];
  const int*   lengths= (const int*)d_in[1];
  const float* Wih0 = (const float*)d_in[2];
  const float* Whh0 = (const float*)d_in[3];
  const float* bih0 = (const float*)d_in[4];
  const float* bhh0 = (const float*)d_in[5];
  const float* WihR = (const float*)d_in[6];
  const float* WhhR = (const float*)d_in[7];
  const float* bihR = (const float*)d_in[8];
  const float* bhhR = (const float*)d_in[9];
  const float* Wout = (const float*)d_in[10];
  const float* bout = (const float*)d_in[11];
  float* out = (float*)d_out;

  char* ws = (char*)d_ws;
  size_t off = 0;
  auto alloc = [&](size_t bytes) -> void* {
    void* p = ws + off; off += (bytes + 255) & ~(size_t)255; return p;
  };
  ushort_t* xin   = (ushort_t*)alloc((size_t)T_*B_*V_*2);
  ushort_t* y0    = (ushort_t*)alloc((size_t)T_*B_*H_*2);
  ushort_t* y1    = (ushort_t*)alloc((size_t)T_*B_*H_*2);
  ushort_t* y2    = (ushort_t*)alloc((size_t)T_*B_*H_*2);
  ushort_t* Wpk0  = (ushort_t*)alloc((size_t)4096*1280*2);
  ushort_t* Wpk1  = (ushort_t*)alloc((size_t)4096*2048*2);
  ushort_t* Wpk2  = (ushort_t*)alloc((size_t)4096*2048*2);
  ushort_t* Woutb = (ushort_t*)alloc((size_t)256*1024*2);
  float*    biaspk= (float*)alloc((size_t)3*4096*4);
  ull*      hbuf  = (ull*)alloc((size_t)3*2*(B_*H_/4)*8);
  int*      syncp = (int*)alloc(256);

  int n;
  n = T_*B_*V_;   k_cvt<<<(n+255)/256, 256, 0, stream>>>(inputs, xin, n);
  n = 256*1024;   k_cvt<<<(n+255)/256, 256, 0, stream>>>(Wout, Woutb, n);
  n = 4096*1280;  k_pack0<<<(n+255)/256, 256, 0, stream>>>(Wih0, Whh0, Wpk0);
  n = 4096*2048;
  k_pack12<<<(n+255)/256, 256, 0, stream>>>(WihR, WhhR, Wpk1);
  k_pack12<<<(n+255)/256, 256, 0, stream>>>(WihR + (size_t)4096*1024,
                                            WhhR + (size_t)4096*1024, Wpk2);
  n = 3*4096;     k_bias<<<(n+255)/256, 256, 0, stream>>>(bih0, bhh0, bihR, bhhR, biaspk);
  { int nz = 3*2*(B_*H_/4); k_zero<<<(nz+255)/256, 256, 0, stream>>>(hbuf, nz, syncp); }

  k_lstm<<<192, 256, 0, stream>>>(xin, Wpk0, Wpk1, Wpk2, biaspk, y0, y1, y2, hbuf, syncp);
  k_out<<<2048, 256, 0, stream>>>(y2, Woutb, bout, lengths, out);
}

// Round 4
// 32116.086 us; speedup vs baseline: 1.0978x; 1.0978x over previous
//
#include <hip/hip_runtime.h>
#include <stdint.h>

#define T_ 512
#define B_ 64
#define V_ 256
#define H_ 1024
#define KMAX 2048

typedef short short8 __attribute__((ext_vector_type(8)));
typedef float float4_ __attribute__((ext_vector_type(4)));
typedef unsigned short ushort_t;
typedef unsigned long long ull;

__device__ __forceinline__ float sigf(float x){ return 1.0f/(1.0f + __expf(-x)); }
__device__ __forceinline__ float tanhfast(float x){ return 1.0f - 2.0f/(__expf(2.0f*x) + 1.0f); }
__device__ __forceinline__ ushort_t f2bf(float x){
  uint32_t u = __float_as_uint(x);
  uint32_t r = (u + 0x7FFFu + ((u >> 16) & 1u)) >> 16;
  return (ushort_t)r;
}

// ---------------- prep kernels ----------------
__global__ void k_cvt(const float* __restrict__ in, ushort_t* __restrict__ out, int n){
  int i = blockIdx.x*256 + threadIdx.x;
  if (i < n) out[i] = f2bf(in[i]);
}

// layer0 packed weights, padded to K=2048: k<256 -> Wih0; 256..1023 -> 0; >=1024 -> Whh0
__global__ void k_pack0(const float* __restrict__ Wih0, const float* __restrict__ Whh0,
                        ushort_t* __restrict__ Wpk){
  int i = blockIdx.x*256 + threadIdx.x;
  if (i >= 4096*2048) return;
  int p = i >> 11, k = i & 2047;
  int col = (p & 3)*1024 + (p >> 2);
  float v = (k < 256) ? Wih0[col*256 + k] : (k < 1024 ? 0.0f : Whh0[col*1024 + (k - 1024)]);
  Wpk[i] = f2bf(v);
}

// layers 1/2: Wpk[p][k], K=2048. k<1024 -> Wih[col][k]; else Whh[col][k-1024]
__global__ void k_pack12(const float* __restrict__ Wih, const float* __restrict__ Whh,
                         ushort_t* __restrict__ Wpk){
  int i = blockIdx.x*256 + threadIdx.x;
  if (i >= 4096*2048) return;
  int p = i >> 11, k = i & 2047;
  int col = (p & 3)*1024 + (p >> 2);
  float v = (k < 1024) ? Wih[col*1024 + k] : Whh[col*1024 + (k - 1024)];
  Wpk[i] = f2bf(v);
}

__global__ void k_bias(const float* __restrict__ bih0, const float* __restrict__ bhh0,
                       const float* __restrict__ bihR, const float* __restrict__ bhhR,
                       float* __restrict__ biaspk){
  int i = blockIdx.x*256 + threadIdx.x;
  if (i >= 3*4096) return;
  int l = i >> 12, p = i & 4095;
  int col = (p & 3)*1024 + (p >> 2);
  float v = (l == 0) ? (bih0[col] + bhh0[col])
                     : (bihR[(l-1)*4096 + col] + bhhR[(l-1)*4096 + col]);
  biaspk[i] = v;
}

__global__ void k_zero(ull* __restrict__ h, int n_ull, int* __restrict__ syncp){
  int i = blockIdx.x*256 + threadIdx.x;
  if (i < n_ull) h[i] = 0ull;
  if (i == 0){ syncp[0] = 0; syncp[1] = 0; }
}

// ---------------- persistent pipelined LSTM, weights in registers ----------------
// 192 blocks: g = bid>>6 (layer), cb = bid&63 -> gate-cols [64*cb,64*cb+64) = hidden j [16*cb,16*cb+16)
// 4 waves split K=2048 (512 each). Weight B-fragments preloaded to VGPRs/AGPRs (64KB/wave).
// y0/y1 are 2-slot ping-pong buffers (consumed exactly 1 superstep after production,
// overwritten 2 supersteps later -> depth 2 suffices). y2 kept full-T for k_out.
__global__ __launch_bounds__(256, 1) void k_lstm(
    const ushort_t* __restrict__ xin,   // [T][B][256] bf16 one-hot
    const ushort_t* __restrict__ Wpk0,
    const ushort_t* __restrict__ Wpk1,
    const ushort_t* __restrict__ Wpk2,
    const float*  __restrict__ biaspk,  // [3][4096]
    ushort_t* ypp,                      // [2 layers][2 slots][B][H] bf16 ping-pong
    ushort_t* y2,                       // [T][B][H] bf16
    ull* hbuf,                          // [3][2][B*H/4]
    int* syncp)
{
  const int tid  = threadIdx.x;
  const int lane = tid & 63;
  const int wv   = tid >> 6;
  const int g    = blockIdx.x >> 6;
  const int cb   = blockIdx.x & 63;
  const int p0   = cb * 64;
  const int j0   = cb * 16;

  const int kxend = (g == 0) ? 256 : 1024;   // valid x-side K extent
  const int sx    = (g == 0) ? 256 : 1024;   // x row stride
  const ushort_t* xbase = (g == 0) ? xin : ypp + (size_t)(g - 1) * 2 * B_ * H_;
  ushort_t* ybase       = (g == 2) ? y2  : ypp + (size_t)g * 2 * B_ * H_;
  const ushort_t* Wpk  = (g == 0) ? Wpk0 : (g == 1 ? Wpk1 : Wpk2);
  const float* bias = biaspk + g*4096;
  ull* hb0 = hbuf + (size_t)g * 2 * (B_*H_/4);

  const int ks = wv * 512;   // this wave's K slice [ks, ks+512)

  // ---- preload weight B-fragments into registers: 8 chunks x 4 ct x 2 = 256 regs ----
  short8 breg[8][4][2];
  #pragma unroll
  for (int c = 0; c < 8; ++c){
    #pragma unroll
    for (int ct = 0; ct < 4; ++ct){
      const ushort_t* pb = Wpk + (size_t)(p0 + ct*16 + (lane & 15)) * KMAX
                               + (ks + c*64) + ((lane >> 4) << 3);
      breg[c][ct][0] = *(const short8*)pb;
      breg[c][ct][1] = *(const short8*)(pb + 32);
    }
  }

  __shared__ float red[2][64][68];   // 34.8 KB partial-sum buffer (padded)

  const int eb = tid >> 2;   // elementwise: batch
  const int jq = tid & 3;    // j quad -> j_local = jq*4 + r
  float c_reg[4] = {0.f, 0.f, 0.f, 0.f};

  int* cnt = syncp; int* gen = syncp + 1;

  for (int s = 0; s < T_ + 2; ++s){
    int t = s - g;
    if (t >= 0 && t < T_){
      const ushort_t* xt = (g == 0) ? xbase + (size_t)t * B_ * 256
                                    : xbase + (size_t)(t & 1) * B_ * H_;
      ushort_t* yt       = (g == 2) ? ybase + (size_t)t * B_ * H_
                                    : ybase + (size_t)(t & 1) * B_ * H_;
      const ushort_t* hcur = (const ushort_t*)(hb0 + (size_t)(t & 1) * (B_*H_/4));
      ull* hnxt = hb0 + (size_t)((t + 1) & 1) * (B_*H_/4);

      float4_ acc[4][4];
      #pragma unroll
      for (int a = 0; a < 4; ++a)
        #pragma unroll
        for (int b = 0; b < 4; ++b){ float4_ z = {0.f,0.f,0.f,0.f}; acc[a][b] = z; }

      #pragma unroll
      for (int c = 0; c < 8; ++c){
        int k0 = ks + c*64;
        short8 av[4][2];
        bool alive = true;
        if (k0 < 1024){
          if (k0 < kxend){
            #pragma unroll
            for (int bt = 0; bt < 4; ++bt){
              int m = bt*16 + (lane & 15);
              const ushort_t* pa = xt + (size_t)m * sx + k0 + ((lane >> 4) << 3);
              av[bt][0] = *(const short8*)pa;
              av[bt][1] = *(const short8*)(pa + 32);
            }
          } else {
            alive = false;   // layer-0 zero-pad region
          }
        } else {
          #pragma unroll
          for (int bt = 0; bt < 4; ++bt){
            int m = bt*16 + (lane & 15);
            const ushort_t* pa = hcur + (size_t)m * 1024 + (k0 - 1024) + ((lane >> 4) << 3);
            av[bt][0] = *(const short8*)pa;
            av[bt][1] = *(const short8*)(pa + 32);
          }
        }
        if (alive){
          #pragma unroll
          for (int ct = 0; ct < 4; ++ct){
            #pragma unroll
            for (int bt = 0; bt < 4; ++bt){
              acc[bt][ct] = __builtin_amdgcn_mfma_f32_16x16x32_bf16(av[bt][0], breg[c][ct][0], acc[bt][ct], 0, 0, 0);
              acc[bt][ct] = __builtin_amdgcn_mfma_f32_16x16x32_bf16(av[bt][1], breg[c][ct][1], acc[bt][ct], 0, 0, 0);
            }
          }
        }
      }

      // cross-wave reduction via LDS
      if (wv < 2){
        #pragma unroll
        for (int bt = 0; bt < 4; ++bt){
          int row = bt*16 + ((lane >> 4) << 2);
          #pragma unroll
          for (int ct = 0; ct < 4; ++ct){
            int colb = ct*16 + (lane & 15);
            #pragma unroll
            for (int r = 0; r < 4; ++r) red[wv][row + r][colb] = acc[bt][ct][r];
          }
        }
      }
      __syncthreads();
      if (wv >= 2){
        #pragma unroll
        for (int bt = 0; bt < 4; ++bt){
          int row = bt*16 + ((lane >> 4) << 2);
          #pragma unroll
          for (int ct = 0; ct < 4; ++ct){
            int colb = ct*16 + (lane & 15);
            #pragma unroll
            for (int r = 0; r < 4; ++r) red[wv - 2][row + r][colb] += acc[bt][ct][r];
          }
        }
      }
      __syncthreads();

      // elementwise LSTM cell for (eb, j_local = jq*4 + r)
      ull hpack = 0ull;
      #pragma unroll
      for (int r = 0; r < 4; ++r){
        int jl = jq*4 + r;
        float4_ a0 = *(float4_*)&red[0][eb][jl*4];
        float4_ a1 = *(float4_*)&red[1][eb][jl*4];
        float4_ bsv = *(const float4_*)(bias + p0 + jl*4);
        float4_ gsv = a0 + a1 + bsv;
        float iv = sigf(gsv.x);
        float fv = sigf(gsv.y);
        float gv = tanhfast(gsv.z);
        float ov = sigf(gsv.w);
        float cv = fv * c_reg[r] + iv * gv;
        c_reg[r] = cv;
        float hv = ov * tanhfast(cv);
        hpack |= ((ull)f2bf(hv)) << (16 * r);
      }
      size_t eo = (size_t)eb * 1024 + j0 + jq*4;
      __hip_atomic_store(hnxt + (eo >> 2), hpack, __ATOMIC_RELAXED, __HIP_MEMORY_SCOPE_AGENT);
      *(ull*)(yt + eo) = hpack;
    }

    // grid barrier (192 blocks, co-resident by construction)
    __builtin_amdgcn_fence(__ATOMIC_RELEASE, "agent");
    __syncthreads();
    if (tid == 0){
      int gv = __hip_atomic_load(gen, __ATOMIC_RELAXED, __HIP_MEMORY_SCOPE_AGENT);
      int a = __hip_atomic_fetch_add(cnt, 1, __ATOMIC_ACQ_REL, __HIP_MEMORY_SCOPE_AGENT);
      if (a == 191){
        __hip_atomic_store(cnt, 0, __ATOMIC_RELAXED, __HIP_MEMORY_SCOPE_AGENT);
        __hip_atomic_store(gen, gv + 1, __ATOMIC_RELEASE, __HIP_MEMORY_SCOPE_AGENT);
      } else {
        while (__hip_atomic_load(gen, __ATOMIC_ACQUIRE, __HIP_MEMORY_SCOPE_AGENT) == gv){
          __builtin_amdgcn_s_sleep(4);
        }
      }
    }
    __syncthreads();
    __builtin_amdgcn_fence(__ATOMIC_ACQUIRE, "agent");
  }
}

// ---------------- output projection ----------------
__global__ __launch_bounds__(256, 1) void k_out(
    const ushort_t* __restrict__ y2, const ushort_t* __restrict__ Woutb,
    const float* __restrict__ bout, const int* __restrict__ lengths,
    float* __restrict__ dout)
{
  int tid = threadIdx.x, lane = tid & 63, wv = tid >> 6;
  int bid = blockIdx.x;
  int b = bid >> 5;
  int rem = bid & 31;
  int vv = rem >> 3, tt = rem & 7;
  int t0 = tt*64 + wv*16;
  float4_ acc[4];
  #pragma unroll
  for (int i = 0; i < 4; ++i){ float4_ z = {0.f,0.f,0.f,0.f}; acc[i] = z; }
  int m = lane & 15, kq = lane >> 4;
  const ushort_t* ya = y2 + ((size_t)(t0 + m) * B_ + b) * H_ + (kq << 3);
  for (int k0 = 0; k0 < 1024; k0 += 32){
    short8 af = *(const short8*)(ya + k0);
    #pragma unroll
    for (int ct = 0; ct < 4; ++ct){
      int v = vv*64 + ct*16 + m;
      short8 bf = *(const short8*)(Woutb + (size_t)v * H_ + k0 + (kq << 3));
      acc[ct] = __builtin_amdgcn_mfma_f32_16x16x32_bf16(af, bf, acc[ct], 0, 0, 0);
    }
  }
  int len = lengths[b];
  int tb = t0 + (kq << 2);
  #pragma unroll
  for (int ct = 0; ct < 4; ++ct){
    int v = vv*64 + ct*16 + m;
    float bo = bout[v];
    float4_ res;
    #pragma unroll
    for (int r = 0; r < 4; ++r){
      int tcur = tb + r;
      res[r] = (tcur < len) ? (acc[ct][r] + bo) : bo;
    }
    *(float4_*)(dout + ((size_t)b * V_ + v) * T_ + tb) = res;
  }
}

extern "C" void kernel_launch(void* const* d_in, const int* in_sizes, int n_in,
                              void* d_out, int out_size, void* d_ws, size_t ws_size,
                              hipStream_t stream){
  const float* inputs = (const float*)d_in[0];
  const int*   lengths= (const int*)d_in[1];
  const float* Wih0 = (const float*)d_in[2];
  const float* Whh0 = (const float*)d_in[3];
  const float* bih0 = (const float*)d_in[4];
  const float* bhh0 = (const float*)d_in[5];
  const float* WihR = (const float*)d_in[6];
  const float* WhhR = (const float*)d_in[7];
  const float* bihR = (const float*)d_in[8];
  const float* bhhR = (const float*)d_in[9];
  const float* Wout = (const float*)d_in[10];
  const float* bout = (const float*)d_in[11];
  float* out = (float*)d_out;

  char* ws = (char*)d_ws;
  size_t off = 0;
  auto alloc = [&](size_t bytes) -> void* {
    void* p = ws + off; off += (bytes + 255) & ~(size_t)255; return p;
  };
  // total ~136 MB (ws_size appears to be 256 MiB; R3's 269.8 MB overflowed it)
  ushort_t* xin   = (ushort_t*)alloc((size_t)T_*B_*V_*2);       // 16.8 MB
  ushort_t* ypp   = (ushort_t*)alloc((size_t)2*2*B_*H_*2);      // 0.5 MB
  ushort_t* y2    = (ushort_t*)alloc((size_t)T_*B_*H_*2);       // 67.1 MB
  ushort_t* Wpk0  = (ushort_t*)alloc((size_t)4096*2048*2);      // 16.8 MB
  ushort_t* Wpk1  = (ushort_t*)alloc((size_t)4096*2048*2);      // 16.8 MB
  ushort_t* Wpk2  = (ushort_t*)alloc((size_t)4096*2048*2);      // 16.8 MB
  ushort_t* Woutb = (ushort_t*)alloc((size_t)256*1024*2);       // 0.5 MB
  float*    biaspk= (float*)alloc((size_t)3*4096*4);            // 48 KB
  ull*      hbuf  = (ull*)alloc((size_t)3*2*(B_*H_/4)*8);       // 0.8 MB
  int*      syncp = (int*)alloc(256);

  int n;
  n = T_*B_*V_;   k_cvt<<<(n+255)/256, 256, 0, stream>>>(inputs, xin, n);
  n = 256*1024;   k_cvt<<<(n+255)/256, 256, 0, stream>>>(Wout, Woutb, n);
  n = 4096*2048;  k_pack0<<<(n+255)/256, 256, 0, stream>>>(Wih0, Whh0, Wpk0);
  k_pack12<<<(n+255)/256, 256, 0, stream>>>(WihR, WhhR, Wpk1);
  k_pack12<<<(n+255)/256, 256, 0, stream>>>(WihR + (size_t)4096*1024,
                                            WhhR + (size_t)4096*1024, Wpk2);
  n = 3*4096;     k_bias<<<(n+255)/256, 256, 0, stream>>>(bih0, bhh0, bihR, bhhR, biaspk);
  { int nz = 3*2*(B_*H_/4); k_zero<<<(nz+255)/256, 256, 0, stream>>>(hbuf, nz, syncp); }

  k_lstm<<<192, 256, 0, stream>>>(xin, Wpk0, Wpk1, Wpk2, biaspk, ypp, y2, hbuf, syncp);
  k_out<<<2048, 256, 0, stream>>>(y2, Woutb, bout, lengths, out);
}

// Round 5
// 8530.829 us; speedup vs baseline: 4.1328x; 3.7647x over previous
//
#include <hip/hip_runtime.h>
#include <stdint.h>

#define T_ 512
#define B_ 64
#define V_ 256
#define H_ 1024
#define KMAX 2048

typedef short short8 __attribute__((ext_vector_type(8)));
typedef float float4_ __attribute__((ext_vector_type(4)));
typedef unsigned short ushort_t;
typedef unsigned long long ull;

__device__ __forceinline__ float sigf(float x){ return 1.0f/(1.0f + __expf(-x)); }
__device__ __forceinline__ float tanhfast(float x){ return 1.0f - 2.0f/(__expf(2.0f*x) + 1.0f); }
__device__ __forceinline__ ushort_t f2bf(float x){
  uint32_t u = __float_as_uint(x);
  uint32_t r = (u + 0x7FFFu + ((u >> 16) & 1u)) >> 16;
  return (ushort_t)r;
}

// ---------------- prep kernels ----------------
__global__ void k_cvt(const float* __restrict__ in, ushort_t* __restrict__ out, int n){
  int i = blockIdx.x*256 + threadIdx.x;
  if (i < n) out[i] = f2bf(in[i]);
}

// layer0 packed weights, padded to K=2048: k<256 -> Wih0; 256..1023 -> 0; >=1024 -> Whh0
__global__ void k_pack0(const float* __restrict__ Wih0, const float* __restrict__ Whh0,
                        ushort_t* __restrict__ Wpk){
  int i = blockIdx.x*256 + threadIdx.x;
  if (i >= 4096*2048) return;
  int p = i >> 11, k = i & 2047;
  int col = (p & 3)*1024 + (p >> 2);
  float v = (k < 256) ? Wih0[col*256 + k] : (k < 1024 ? 0.0f : Whh0[col*1024 + (k - 1024)]);
  Wpk[i] = f2bf(v);
}

// layers 1/2: Wpk[p][k], K=2048. k<1024 -> Wih[col][k]; else Whh[col][k-1024]
__global__ void k_pack12(const float* __restrict__ Wih, const float* __restrict__ Whh,
                         ushort_t* __restrict__ Wpk){
  int i = blockIdx.x*256 + threadIdx.x;
  if (i >= 4096*2048) return;
  int p = i >> 11, k = i & 2047;
  int col = (p & 3)*1024 + (p >> 2);
  float v = (k < 1024) ? Wih[col*1024 + k] : Whh[col*1024 + (k - 1024)];
  Wpk[i] = f2bf(v);
}

__global__ void k_bias(const float* __restrict__ bih0, const float* __restrict__ bhh0,
                       const float* __restrict__ bihR, const float* __restrict__ bhhR,
                       float* __restrict__ biaspk){
  int i = blockIdx.x*256 + threadIdx.x;
  if (i >= 3*4096) return;
  int l = i >> 12, p = i & 4095;
  int col = (p & 3)*1024 + (p >> 2);
  float v = (l == 0) ? (bih0[col] + bhh0[col])
                     : (bihR[(l-1)*4096 + col] + bhhR[(l-1)*4096 + col]);
  biaspk[i] = v;
}

__global__ void k_zero(ull* __restrict__ h, int n_ull, int* __restrict__ flags, int nf){
  int i = blockIdx.x*256 + threadIdx.x;
  if (i < n_ull) h[i] = 0ull;
  if (i < nf) flags[i] = 0;
}

// ---------------- persistent pipelined LSTM, weights in registers ----------------
// 192 blocks: g = bid>>6 (layer), cb = bid&63 -> gate-cols [64*cb,64*cb+64) = hidden j [16*cb,16*cb+16)
// 4 waves split K=2048 (512 each). Weight B-fragments preloaded to VGPRs/AGPRs (64KB/wave).
// Grid sync: flag-array barrier (zero serialized RMWs; R4's single-counter fetch_add
// serialized 192 cross-XCD RMWs ~= 58us/superstep — the measured 62us/step bottleneck).
__global__ __launch_bounds__(256, 1) void k_lstm(
    const ushort_t* __restrict__ xin,   // [T][B][256] bf16 one-hot
    const ushort_t* __restrict__ Wpk0,
    const ushort_t* __restrict__ Wpk1,
    const ushort_t* __restrict__ Wpk2,
    const float*  __restrict__ biaspk,  // [3][4096]
    ushort_t* ypp,                      // [2 layers][2 slots][B][H] bf16 ping-pong
    ushort_t* y2,                       // [T][B][H] bf16
    ull* hbuf,                          // [3][2][B*H/4]
    int* flags)                         // [192][16] arrival flags (64B-padded)
{
  const int tid  = threadIdx.x;
  const int lane = tid & 63;
  const int wv   = tid >> 6;
  const int g    = blockIdx.x >> 6;
  const int cb   = blockIdx.x & 63;
  const int p0   = cb * 64;
  const int j0   = cb * 16;

  const int kxend = (g == 0) ? 256 : 1024;   // valid x-side K extent
  const int sx    = (g == 0) ? 256 : 1024;   // x row stride
  const ushort_t* xbase = (g == 0) ? xin : ypp + (size_t)(g - 1) * 2 * B_ * H_;
  ushort_t* ybase       = (g == 2) ? y2  : ypp + (size_t)g * 2 * B_ * H_;
  const ushort_t* Wpk  = (g == 0) ? Wpk0 : (g == 1 ? Wpk1 : Wpk2);
  const float* bias = biaspk + g*4096;
  ull* hb0 = hbuf + (size_t)g * 2 * (B_*H_/4);

  const int ks = wv * 512;   // this wave's K slice [ks, ks+512)

  // ---- preload weight B-fragments into registers: 8 chunks x 4 ct x 2 = 256 regs ----
  short8 breg[8][4][2];
  #pragma unroll
  for (int c = 0; c < 8; ++c){
    #pragma unroll
    for (int ct = 0; ct < 4; ++ct){
      const ushort_t* pb = Wpk + (size_t)(p0 + ct*16 + (lane & 15)) * KMAX
                               + (ks + c*64) + ((lane >> 4) << 3);
      breg[c][ct][0] = *(const short8*)pb;
      breg[c][ct][1] = *(const short8*)(pb + 32);
    }
  }

  __shared__ float red[2][64][68];   // 34.8 KB partial-sum buffer (padded)

  const int eb = tid >> 2;   // elementwise: batch
  const int jq = tid & 3;    // j quad -> j_local = jq*4 + r
  float c_reg[4] = {0.f, 0.f, 0.f, 0.f};

  for (int s = 0; s < T_ + 2; ++s){
    int t = s - g;
    if (t >= 0 && t < T_){
      const ushort_t* xt = (g == 0) ? xbase + (size_t)t * B_ * 256
                                    : xbase + (size_t)(t & 1) * B_ * H_;
      ushort_t* yt       = (g == 2) ? ybase + (size_t)t * B_ * H_
                                    : ybase + (size_t)(t & 1) * B_ * H_;
      const ushort_t* hcur = (const ushort_t*)(hb0 + (size_t)(t & 1) * (B_*H_/4));
      ull* hnxt = hb0 + (size_t)((t + 1) & 1) * (B_*H_/4);

      float4_ acc[4][4];
      #pragma unroll
      for (int a = 0; a < 4; ++a)
        #pragma unroll
        for (int b = 0; b < 4; ++b){ float4_ z = {0.f,0.f,0.f,0.f}; acc[a][b] = z; }

      #pragma unroll
      for (int c = 0; c < 8; ++c){
        int k0 = ks + c*64;
        short8 av[4][2];
        bool alive = true;
        if (k0 < 1024){
          if (k0 < kxend){
            #pragma unroll
            for (int bt = 0; bt < 4; ++bt){
              int m = bt*16 + (lane & 15);
              const ushort_t* pa = xt + (size_t)m * sx + k0 + ((lane >> 4) << 3);
              av[bt][0] = *(const short8*)pa;
              av[bt][1] = *(const short8*)(pa + 32);
            }
          } else {
            alive = false;   // layer-0 zero-pad region
          }
        } else {
          #pragma unroll
          for (int bt = 0; bt < 4; ++bt){
            int m = bt*16 + (lane & 15);
            const ushort_t* pa = hcur + (size_t)m * 1024 + (k0 - 1024) + ((lane >> 4) << 3);
            av[bt][0] = *(const short8*)pa;
            av[bt][1] = *(const short8*)(pa + 32);
          }
        }
        if (alive){
          #pragma unroll
          for (int ct = 0; ct < 4; ++ct){
            #pragma unroll
            for (int bt = 0; bt < 4; ++bt){
              acc[bt][ct] = __builtin_amdgcn_mfma_f32_16x16x32_bf16(av[bt][0], breg[c][ct][0], acc[bt][ct], 0, 0, 0);
              acc[bt][ct] = __builtin_amdgcn_mfma_f32_16x16x32_bf16(av[bt][1], breg[c][ct][1], acc[bt][ct], 0, 0, 0);
            }
          }
        }
      }

      // cross-wave reduction via LDS
      if (wv < 2){
        #pragma unroll
        for (int bt = 0; bt < 4; ++bt){
          int row = bt*16 + ((lane >> 4) << 2);
          #pragma unroll
          for (int ct = 0; ct < 4; ++ct){
            int colb = ct*16 + (lane & 15);
            #pragma unroll
            for (int r = 0; r < 4; ++r) red[wv][row + r][colb] = acc[bt][ct][r];
          }
        }
      }
      __syncthreads();
      if (wv >= 2){
        #pragma unroll
        for (int bt = 0; bt < 4; ++bt){
          int row = bt*16 + ((lane >> 4) << 2);
          #pragma unroll
          for (int ct = 0; ct < 4; ++ct){
            int colb = ct*16 + (lane & 15);
            #pragma unroll
            for (int r = 0; r < 4; ++r) red[wv - 2][row + r][colb] += acc[bt][ct][r];
          }
        }
      }
      __syncthreads();

      // elementwise LSTM cell for (eb, j_local = jq*4 + r)
      ull hpack = 0ull;
      #pragma unroll
      for (int r = 0; r < 4; ++r){
        int jl = jq*4 + r;
        float4_ a0 = *(float4_*)&red[0][eb][jl*4];
        float4_ a1 = *(float4_*)&red[1][eb][jl*4];
        float4_ bsv = *(const float4_*)(bias + p0 + jl*4);
        float4_ gsv = a0 + a1 + bsv;
        float iv = sigf(gsv.x);
        float fv = sigf(gsv.y);
        float gv = tanhfast(gsv.z);
        float ov = sigf(gsv.w);
        float cv = fv * c_reg[r] + iv * gv;
        c_reg[r] = cv;
        float hv = ov * tanhfast(cv);
        hpack |= ((ull)f2bf(hv)) << (16 * r);
      }
      size_t eo = (size_t)eb * 1024 + j0 + jq*4;
      __hip_atomic_store(hnxt + (eo >> 2), hpack, __ATOMIC_RELAXED, __HIP_MEMORY_SCOPE_AGENT);
      if (g == 2){
        *(ull*)(yt + eo) = hpack;   // consumed only by k_out after kernel end
      } else {
        __hip_atomic_store((ull*)(yt + eo), hpack, __ATOMIC_RELAXED, __HIP_MEMORY_SCOPE_AGENT);
      }
    }

    // ---- flag-array grid barrier (192 blocks, co-resident; no serialized RMWs) ----
    __syncthreads();   // drains each thread's vmcnt -> all sc1 data stores MALL-visible
    if (tid == 0){
      __hip_atomic_store(flags + (size_t)blockIdx.x * 16, s + 1,
                         __ATOMIC_RELAXED, __HIP_MEMORY_SCOPE_AGENT);
    }
    asm volatile("" ::: "memory");   // keep poll below own-flag store
    if (tid < 192){
      const int* fp = flags + (size_t)tid * 16;
      while (__hip_atomic_load(fp, __ATOMIC_RELAXED, __HIP_MEMORY_SCOPE_AGENT) < s + 1){
        __builtin_amdgcn_s_sleep(8);
      }
    }
    __syncthreads();
    // acquire: invalidate L1/L2 so plain A-loads next superstep see fresh h/ypp
    __builtin_amdgcn_fence(__ATOMIC_ACQUIRE, "agent");
  }
}

// ---------------- output projection ----------------
__global__ __launch_bounds__(256, 1) void k_out(
    const ushort_t* __restrict__ y2, const ushort_t* __restrict__ Woutb,
    const float* __restrict__ bout, const int* __restrict__ lengths,
    float* __restrict__ dout)
{
  int tid = threadIdx.x, lane = tid & 63, wv = tid >> 6;
  int bid = blockIdx.x;
  int b = bid >> 5;
  int rem = bid & 31;
  int vv = rem >> 3, tt = rem & 7;
  int t0 = tt*64 + wv*16;
  float4_ acc[4];
  #pragma unroll
  for (int i = 0; i < 4; ++i){ float4_ z = {0.f,0.f,0.f,0.f}; acc[i] = z; }
  int m = lane & 15, kq = lane >> 4;
  const ushort_t* ya = y2 + ((size_t)(t0 + m) * B_ + b) * H_ + (kq << 3);
  for (int k0 = 0; k0 < 1024; k0 += 32){
    short8 af = *(const short8*)(ya + k0);
    #pragma unroll
    for (int ct = 0; ct < 4; ++ct){
      int v = vv*64 + ct*16 + m;
      short8 bf = *(const short8*)(Woutb + (size_t)v * H_ + k0 + (kq << 3));
      acc[ct] = __builtin_amdgcn_mfma_f32_16x16x32_bf16(af, bf, acc[ct], 0, 0, 0);
    }
  }
  int len = lengths[b];
  int tb = t0 + (kq << 2);
  #pragma unroll
  for (int ct = 0; ct < 4; ++ct){
    int v = vv*64 + ct*16 + m;
    float bo = bout[v];
    float4_ res;
    #pragma unroll
    for (int r = 0; r < 4; ++r){
      int tcur = tb + r;
      res[r] = (tcur < len) ? (acc[ct][r] + bo) : bo;
    }
    *(float4_*)(dout + ((size_t)b * V_ + v) * T_ + tb) = res;
  }
}

extern "C" void kernel_launch(void* const* d_in, const int* in_sizes, int n_in,
                              void* d_out, int out_size, void* d_ws, size_t ws_size,
                              hipStream_t stream){
  const float* inputs = (const float*)d_in[0];
  const int*   lengths= (const int*)d_in[1];
  const float* Wih0 = (const float*)d_in[2];
  const float* Whh0 = (const float*)d_in[3];
  const float* bih0 = (const float*)d_in[4];
  const float* bhh0 = (const float*)d_in[5];
  const float* WihR = (const float*)d_in[6];
  const float* WhhR = (const float*)d_in[7];
  const float* bihR = (const float*)d_in[8];
  const float* bhhR = (const float*)d_in[9];
  const float* Wout = (const float*)d_in[10];
  const float* bout = (const float*)d_in[11];
  float* out = (float*)d_out;

  char* ws = (char*)d_ws;
  size_t off = 0;
  auto alloc = [&](size_t bytes) -> void* {
    void* p = ws + off; off += (bytes + 255) & ~(size_t)255; return p;
  };
  // total ~136 MB (R3's 269.8 MB overflowed ws_size)
  ushort_t* xin   = (ushort_t*)alloc((size_t)T_*B_*V_*2);       // 16.8 MB
  ushort_t* ypp   = (ushort_t*)alloc((size_t)2*2*B_*H_*2);      // 0.5 MB
  ushort_t* y2    = (ushort_t*)alloc((size_t)T_*B_*H_*2);       // 67.1 MB
  ushort_t* Wpk0  = (ushort_t*)alloc((size_t)4096*2048*2);      // 16.8 MB
  ushort_t* Wpk1  = (ushort_t*)alloc((size_t)4096*2048*2);      // 16.8 MB
  ushort_t* Wpk2  = (ushort_t*)alloc((size_t)4096*2048*2);      // 16.8 MB
  ushort_t* Woutb = (ushort_t*)alloc((size_t)256*1024*2);       // 0.5 MB
  float*    biaspk= (float*)alloc((size_t)3*4096*4);            // 48 KB
  ull*      hbuf  = (ull*)alloc((size_t)3*2*(B_*H_/4)*8);       // 0.8 MB
  int*      flags = (int*)alloc(16384);                         // 192*16 ints, 64B-padded

  int n;
  n = T_*B_*V_;   k_cvt<<<(n+255)/256, 256, 0, stream>>>(inputs, xin, n);
  n = 256*1024;   k_cvt<<<(n+255)/256, 256, 0, stream>>>(Wout, Woutb, n);
  n = 4096*2048;  k_pack0<<<(n+255)/256, 256, 0, stream>>>(Wih0, Whh0, Wpk0);
  k_pack12<<<(n+255)/256, 256, 0, stream>>>(WihR, WhhR, Wpk1);
  k_pack12<<<(n+255)/256, 256, 0, stream>>>(WihR + (size_t)4096*1024,
                                            WhhR + (size_t)4096*1024, Wpk2);
  n = 3*4096;     k_bias<<<(n+255)/256, 256, 0, stream>>>(bih0, bhh0, bihR, bhhR, biaspk);
  { int nz = 3*2*(B_*H_/4); k_zero<<<(nz+255)/256, 256, 0, stream>>>(hbuf, nz, flags, 4096); }

  k_lstm<<<192, 256, 0, stream>>>(xin, Wpk0, Wpk1, Wpk2, biaspk, ypp, y2, hbuf, flags);
  k_out<<<2048, 256, 0, stream>>>(y2, Woutb, bout, lengths, out);
}